// Round 2
// baseline (285.998 us; speedup 1.0000x reference)
//
#include <hip/hip_runtime.h>
#include <hip/hip_bf16.h>
#include <cstdint>
#include <cstddef>

// Problem constants
#define B_   2
#define S_   2048
#define H_   1024
#define NH   16
#define DH   64
#define SCALE 0.125f   // D^-0.5

typedef __hip_bfloat16 bf16;
typedef short bf16x8 __attribute__((ext_vector_type(8)));   // 8 bf16 in 4 VGPRs
typedef float f32x4 __attribute__((ext_vector_type(4)));

#define MFMA16(a, b, c) __builtin_amdgcn_mfma_f32_16x16x32_bf16((a), (b), (c), 0, 0, 0)

__device__ __forceinline__ void async16(const void* g, void* l) {
  __builtin_amdgcn_global_load_lds(
      (const __attribute__((address_space(1))) void*)g,
      (__attribute__((address_space(3))) void*)l,
      16, 0, 0);
}

// ---------------------------------------------------------------------------
// f32 -> bf16 elementwise convert (4 elems/thread)
// ---------------------------------------------------------------------------
__global__ void convert_f32_bf16(const float* __restrict__ src, bf16* __restrict__ dst,
                                 int n) {
  int i = (blockIdx.x * 256 + threadIdx.x) * 4;
  if (i + 3 < n) {
    float4 v = *(const float4*)(src + i);
    dst[i + 0] = __float2bfloat16(v.x);
    dst[i + 1] = __float2bfloat16(v.y);
    dst[i + 2] = __float2bfloat16(v.z);
    dst[i + 3] = __float2bfloat16(v.w);
  }
}

// ---------------------------------------------------------------------------
// f32 -> bf16 transpose: dst[c][r] = (bf16)src[r][c]. grid (C/32, R/32), blk 256
// ---------------------------------------------------------------------------
__global__ void transpose_f32_bf16(const float* __restrict__ src, bf16* __restrict__ dst,
                                   int R, int C) {
  __shared__ bf16 tile[32][33];
  int c0 = blockIdx.x * 32, r0 = blockIdx.y * 32;
  int tx = threadIdx.x & 31, ty = threadIdx.x >> 5;   // 32 x 8
  for (int i = 0; i < 32; i += 8)
    tile[ty + i][tx] = __float2bfloat16(src[(size_t)(r0 + ty + i) * C + c0 + tx]);
  __syncthreads();
  for (int i = 0; i < 32; i += 8)
    dst[(size_t)(c0 + ty + i) * R + r0 + tx] = tile[tx][ty + i];
}

// ---------------------------------------------------------------------------
// bf16 -> bf16 batched transpose (for V): dst[z][c][r] = src[z][r][c]
// grid: (C/32, R/32, batch), block 256
// ---------------------------------------------------------------------------
__global__ void transpose_bf16(const bf16* __restrict__ src, bf16* __restrict__ dst,
                               int R, int C) {
  __shared__ bf16 tile[32][33];
  size_t bofs = (size_t)blockIdx.z * R * C;
  int c0 = blockIdx.x * 32, r0 = blockIdx.y * 32;
  int tx = threadIdx.x & 31, ty = threadIdx.x >> 5;
  for (int i = 0; i < 32; i += 8)
    tile[ty + i][tx] = src[bofs + (size_t)(r0 + ty + i) * C + c0 + tx];
  __syncthreads();
  for (int i = 0; i < 32; i += 8)
    dst[bofs + (size_t)(c0 + ty + i) * R + r0 + tx] = tile[tx][ty + i];
}

// ---------------------------------------------------------------------------
// rpe cumsum: cum[n][t] = sum_{u<=t} rpe[n][u]  (f32 in, f32 out). grid NH
// ---------------------------------------------------------------------------
__global__ void rpe_scan(const float* __restrict__ rpe, float* __restrict__ cum) {
  __shared__ float ssum[256];
  int n = blockIdx.x, t = threadIdx.x;
  float loc[8];
  float s = 0.f;
  int base = t * 8;
  for (int u = 0; u < 8; ++u) {
    loc[u] = rpe[n * S_ + base + u];
    s += loc[u];
  }
  ssum[t] = s;
  __syncthreads();
  float own = s;
  for (int off = 1; off < 256; off <<= 1) {
    float v = (t >= off) ? ssum[t - off] : 0.f;
    __syncthreads();
    ssum[t] += v;
    __syncthreads();
  }
  float run = ssum[t] - own;   // exclusive prefix of this thread's chunk
  for (int u = 0; u < 8; ++u) {
    run += loc[u];
    cum[n * S_ + base + u] = run;
  }
}

// ---------------------------------------------------------------------------
// GEMM: C[M x Nc] = A[M x 1024] * Bt[Nc x 1024]^T, bf16 in, f32 acc.
// 128x128 tile, BK=32, 256 threads (4 waves, 2x2 of 64x64).
// MODE 0: scatter epilogue into q/k/v bf16 buffers ([b,n,s,d]);  Nc=3072
// MODE 1: f32 store to F0, row stride 1024;                      Nc=1024
// ---------------------------------------------------------------------------
template <int MODE>
__global__ __launch_bounds__(256, 2)
void gemm_bt(const bf16* __restrict__ A, const bf16* __restrict__ Bt,
             bf16* __restrict__ C0, bf16* __restrict__ C1, bf16* __restrict__ C2,
             float* __restrict__ F0) {
  __shared__ bf16 As[128 * 32] __attribute__((aligned(16)));
  __shared__ bf16 Bs[128 * 32] __attribute__((aligned(16)));
  const int tid = threadIdx.x, lane = tid & 63, w = tid >> 6;
  const int lr = lane & 15, lq = lane >> 4;
  const int m0 = blockIdx.y * 128, n0 = blockIdx.x * 128;
  const int wm = (w & 1) * 64, wn = (w >> 1) * 64;

  f32x4 acc[4][4] = {};

  for (int k0 = 0; k0 < 1024; k0 += 32) {
    __syncthreads();
    for (int t = 0; t < 2; ++t) {
      int c = (t * 4 + w) * 64 + lane;          // chunk id 0..511
      int row = c >> 2, k8 = (c & 3) * 8;
      async16(A + (size_t)(m0 + row) * 1024 + k0 + k8,
              (char*)As + (size_t)(t * 4 + w) * 1024 + lane * 16);
      async16(Bt + (size_t)(n0 + row) * 1024 + k0 + k8,
              (char*)Bs + (size_t)(t * 4 + w) * 1024 + lane * 16);
    }
    __syncthreads();
    bf16x8 af[4], bfr[4];
#pragma unroll
    for (int mt = 0; mt < 4; ++mt)
      af[mt] = *(const bf16x8*)(As + (wm + mt * 16 + lr) * 32 + lq * 8);
#pragma unroll
    for (int nt = 0; nt < 4; ++nt)
      bfr[nt] = *(const bf16x8*)(Bs + (wn + nt * 16 + lr) * 32 + lq * 8);
#pragma unroll
    for (int mt = 0; mt < 4; ++mt)
#pragma unroll
      for (int nt = 0; nt < 4; ++nt)
        acc[mt][nt] = MFMA16(af[mt], bfr[nt], acc[mt][nt]);
  }

  if (MODE == 0) {
    // col cN in [0,3072): m = cN>>10 (q/k/v), n = (cN>>6)&15, d = cN&63
#pragma unroll
    for (int nt = 0; nt < 4; ++nt) {
      int cN = n0 + wn + nt * 16 + lr;
      int mm = cN >> 10, nn = (cN >> 6) & 15, dd = cN & 63;
      bf16* dst = mm == 0 ? C0 : (mm == 1 ? C1 : C2);
#pragma unroll
      for (int mt = 0; mt < 4; ++mt)
#pragma unroll
        for (int r = 0; r < 4; ++r) {
          int rM = m0 + wm + mt * 16 + lq * 4 + r;   // b*S + s
          int bb = rM >> 11, ss = rM & 2047;
          dst[((size_t)(bb * NH + nn) * S_ + ss) * DH + dd] =
              __float2bfloat16(acc[mt][nt][r]);
        }
    }
  } else {
#pragma unroll
    for (int mt = 0; mt < 4; ++mt)
#pragma unroll
      for (int nt = 0; nt < 4; ++nt)
#pragma unroll
        for (int r = 0; r < 4; ++r) {
          int rM = m0 + wm + mt * 16 + lq * 4 + r;
          int cN = n0 + wn + nt * 16 + lr;
          F0[(size_t)rM * 1024 + cN] = acc[mt][nt][r];
        }
  }
}

// ---------------------------------------------------------------------------
// Flash attention, causal + cumulative rpe bias.
// q,k: [bn][S][D] bf16;  vt: [bn][D][S] bf16;  cum: [N][S] f32
// mix out: [b][s][n][d] bf16
// grid (8, B*N), block 512 (8 waves). Block does Q-tiles {bx, 15-bx}.
// LDS: K (16KB) aliased under P (128x136 bf16 = 34 KB), Vt 16 KB at +34816.
// ---------------------------------------------------------------------------
__global__ __launch_bounds__(512, 2)
void fa_kernel(const bf16* __restrict__ q, const bf16* __restrict__ k,
               const bf16* __restrict__ vt, const float* __restrict__ cum,
               bf16* __restrict__ mix) {
  __shared__ char smem[34816 + 16384] __attribute__((aligned(16)));
  bf16* Ks = (bf16*)smem;            // [128][64]
  bf16* Ps = (bf16*)smem;            // [128][136] (aliases K region)
  bf16* Vs = (bf16*)(smem + 34816);  // [64][128]

  const int tid = threadIdx.x, lane = tid & 63, w = tid >> 6;  // w: 0..7
  const int lr = lane & 15, lq = lane >> 4;
  const int bn = blockIdx.y;
  const int n = bn & (NH - 1);
  const int b = bn >> 4;
  const float* cumn = cum + n * S_;

  for (int tt = 0; tt < 2; ++tt) {
    const int ti = (tt == 0) ? blockIdx.x : 15 - blockIdx.x;
    const int i0 = ti * 128;

    // Q fragments for this wave's 16 rows (A-operand layout)
    const bf16* qbase = q + ((size_t)bn * S_ + i0 + w * 16) * DH;
    bf16x8 qf[2];
#pragma unroll
    for (int kt = 0; kt < 2; ++kt)
      qf[kt] = *(const bf16x8*)(qbase + lr * DH + kt * 32 + lq * 8);

    f32x4 oacc[4] = {};
    float m_i[4], l_i[4];
#pragma unroll
    for (int r = 0; r < 4; ++r) { m_i[r] = -1e30f; l_i[r] = 0.f; }

    for (int jt = 0; jt <= ti; ++jt) {
      const int j0 = jt * 128;
      __syncthreads();   // P/V regions free to overwrite
      const char* ksrc = (const char*)(k + ((size_t)bn * S_ + j0) * DH);
#pragma unroll
      for (int t = 0; t < 2; ++t) {
        int cb = t * 8 + w;
        async16(ksrc + cb * 1024 + lane * 16, smem + cb * 1024 + lane * 16);
      }
#pragma unroll
      for (int t = 0; t < 2; ++t) {
        int c = (t * 8 + w) * 64 + lane;     // 0..1023
        int d = c >> 4, sc = (c & 15) * 8;
        async16((const char*)(vt + ((size_t)bn * DH + d) * S_ + j0 + sc),
                smem + 34816 + (t * 8 + w) * 1024 + lane * 16);
      }
      __syncthreads();   // staging complete

      // S = Q K^T  (wave's 16 rows x 128 cols)
      f32x4 sa[8] = {};
#pragma unroll
      for (int kt = 0; kt < 2; ++kt)
#pragma unroll
        for (int nt = 0; nt < 8; ++nt) {
          bf16x8 kf = *(const bf16x8*)(Ks + (nt * 16 + lr) * DH + kt * 32 + lq * 8);
          sa[nt] = MFMA16(qf[kt], kf, sa[nt]);
        }
      __syncthreads();   // everyone done reading Ks before P overwrites it

      // scale + bias + causal mask; track row maxes
      const int ibase = i0 + w * 16 + lq * 4;
      float rmax[4] = {-1e30f, -1e30f, -1e30f, -1e30f};
#pragma unroll
      for (int nt = 0; nt < 8; ++nt) {
        int jcol = j0 + nt * 16 + lr;
#pragma unroll
        for (int r = 0; r < 4; ++r) {
          int dd = ibase + r - jcol;
          float val = -1e30f;
          if (dd >= 0) val = sa[nt][r] * SCALE + cumn[dd];
          sa[nt][r] = val;
          rmax[r] = fmaxf(rmax[r], val);
        }
      }
      // online softmax per row (row owned by 16 consecutive lanes)
#pragma unroll
      for (int r = 0; r < 4; ++r) {
        float mx = rmax[r];
        mx = fmaxf(mx, __shfl_xor(mx, 1));
        mx = fmaxf(mx, __shfl_xor(mx, 2));
        mx = fmaxf(mx, __shfl_xor(mx, 4));
        mx = fmaxf(mx, __shfl_xor(mx, 8));
        float newm = fmaxf(m_i[r], mx);
        float al = __expf(m_i[r] - newm);
        m_i[r] = newm;
        float rs = 0.f;
#pragma unroll
        for (int nt = 0; nt < 8; ++nt) {
          float p = __expf(sa[nt][r] - newm);
          sa[nt][r] = p;
          rs += p;
        }
        rs += __shfl_xor(rs, 1);
        rs += __shfl_xor(rs, 2);
        rs += __shfl_xor(rs, 4);
        rs += __shfl_xor(rs, 8);
        l_i[r] = l_i[r] * al + rs;
#pragma unroll
        for (int dt = 0; dt < 4; ++dt) oacc[dt][r] *= al;
      }
      // write P (bf16) to this wave's private 16 rows
#pragma unroll
      for (int nt = 0; nt < 8; ++nt)
#pragma unroll
        for (int r = 0; r < 4; ++r)
          Ps[(w * 16 + lq * 4 + r) * 136 + nt * 16 + lr] =
              __float2bfloat16(sa[nt][r]);

      // O += P V (wave-private P rows; in-wave DS ordering suffices)
#pragma unroll
      for (int kt2 = 0; kt2 < 4; ++kt2) {
        bf16x8 pf = *(const bf16x8*)(Ps + (w * 16 + lr) * 136 + kt2 * 32 + lq * 8);
#pragma unroll
        for (int dt = 0; dt < 4; ++dt) {
          bf16x8 vf = *(const bf16x8*)(Vs + (dt * 16 + lr) * 128 + kt2 * 32 + lq * 8);
          oacc[dt] = MFMA16(pf, vf, oacc[dt]);
        }
      }
    }

    // epilogue: mix[b][s][n][d]
#pragma unroll
    for (int dt = 0; dt < 4; ++dt)
#pragma unroll
      for (int r = 0; r < 4; ++r) {
        int i = i0 + w * 16 + lq * 4 + r;
        int d = dt * 16 + lr;
        mix[((size_t)(b * S_ + i) * NH + n) * DH + d] =
            __float2bfloat16(oacc[dt][r] / l_i[r]);
      }
  }
}

// ---------------------------------------------------------------------------
extern "C" void kernel_launch(void* const* d_in, const int* in_sizes, int n_in,
                              void* d_out, int out_size, void* d_ws, size_t ws_size,
                              hipStream_t stream) {
  const float* x     = (const float*)d_in[0];   // [B,S,H] f32
  const float* qkv   = (const float*)d_in[1];   // [H,3,N,D] f32 == [1024][3072]
  const float* out_w = (const float*)d_in[2];   // [N,D,H] f32   == [1024][1024]
  const float* rpe   = (const float*)d_in[3];   // [N,S] f32
  float* out = (float*)d_out;                   // [B,S,H] f32

  char* ws = (char*)d_ws;
  bf16* qkvT  = (bf16*)(ws + 0);          // [3072][1024] bf16   6291456 B
  bf16* outwT = (bf16*)(ws + 6291456);    // [1024][1024] bf16   2097152 B
  bf16* xb    = (bf16*)(ws + 8388608);    // [4096][1024] bf16   8388608 B
  bf16* qb    = (bf16*)(ws + 16777216);   // [bn][S][D]          8388608 B
  bf16* kb    = (bf16*)(ws + 25165824);   // [bn][S][D]          8388608 B
  bf16* vb    = (bf16*)(ws + 33554432);   // [bn][S][D]          8388608 B
  bf16* vtb   = (bf16*)(ws + 41943040);   // [bn][D][S]          8388608 B
  bf16* mixb  = (bf16*)(ws + 50331648);   // [b][s][n][d]        8388608 B
  float* cum  = (float*)(ws + 58720256);  // [N][S] f32           131072 B

  // 1. convert x; pre-transpose+convert weights
  convert_f32_bf16<<<4096, 256, 0, stream>>>(x, xb, 4096 * 1024);
  transpose_f32_bf16<<<dim3(3072 / 32, 1024 / 32), 256, 0, stream>>>(qkv, qkvT, 1024, 3072);
  transpose_f32_bf16<<<dim3(1024 / 32, 1024 / 32), 256, 0, stream>>>(out_w, outwT, 1024, 1024);
  // 2. rpe cumsum
  rpe_scan<<<NH, 256, 0, stream>>>(rpe, cum);
  // 3. QKV projection
  gemm_bt<0><<<dim3(3072 / 128, 4096 / 128), 256, 0, stream>>>(xb, qkvT, qb, kb, vb, nullptr);
  // 4. transpose V per (b,n)
  transpose_bf16<<<dim3(DH / 32, S_ / 32, B_ * NH), 256, 0, stream>>>(vb, vtb, S_, DH);
  // 5. attention
  fa_kernel<<<dim3(8, B_ * NH), 512, 0, stream>>>(qb, kb, vtb, cum, mixb);
  // 6. output projection (f32 out)
  gemm_bt<1><<<dim3(1024 / 128, 4096 / 128), 256, 0, stream>>>(mixb, outwT, nullptr, nullptr, nullptr, out);
}

// Round 3
// 268.191 us; speedup vs baseline: 1.0664x; 1.0664x over previous
//
#include <hip/hip_runtime.h>
#include <hip/hip_bf16.h>
#include <cstdint>
#include <cstddef>

// Problem constants
#define B_   2
#define S_   2048
#define H_   1024
#define NH   16
#define DH   64
#define SCALE 0.125f   // D^-0.5

typedef __hip_bfloat16 bf16;
typedef short bf16x8 __attribute__((ext_vector_type(8)));   // 8 bf16 in 4 VGPRs
typedef float f32x4 __attribute__((ext_vector_type(4)));

#define MFMA16(a, b, c) __builtin_amdgcn_mfma_f32_16x16x32_bf16((a), (b), (c), 0, 0, 0)

__device__ __forceinline__ void async16(const void* g, void* l) {
  __builtin_amdgcn_global_load_lds(
      (const __attribute__((address_space(1))) void*)g,
      (__attribute__((address_space(3))) void*)l,
      16, 0, 0);
}

// ---------------------------------------------------------------------------
// f32 -> bf16 elementwise convert (4 elems/thread)
// ---------------------------------------------------------------------------
__global__ void convert_f32_bf16(const float* __restrict__ src, bf16* __restrict__ dst,
                                 int n) {
  int i = (blockIdx.x * 256 + threadIdx.x) * 4;
  if (i + 3 < n) {
    float4 v = *(const float4*)(src + i);
    dst[i + 0] = __float2bfloat16(v.x);
    dst[i + 1] = __float2bfloat16(v.y);
    dst[i + 2] = __float2bfloat16(v.z);
    dst[i + 3] = __float2bfloat16(v.w);
  }
}

// ---------------------------------------------------------------------------
// f32 -> bf16 transpose: dst[c][r] = (bf16)src[r][c]. grid (C/32, R/32), blk 256
// ---------------------------------------------------------------------------
__global__ void transpose_f32_bf16(const float* __restrict__ src, bf16* __restrict__ dst,
                                   int R, int C) {
  __shared__ bf16 tile[32][33];
  int c0 = blockIdx.x * 32, r0 = blockIdx.y * 32;
  int tx = threadIdx.x & 31, ty = threadIdx.x >> 5;   // 32 x 8
  for (int i = 0; i < 32; i += 8)
    tile[ty + i][tx] = __float2bfloat16(src[(size_t)(r0 + ty + i) * C + c0 + tx]);
  __syncthreads();
  for (int i = 0; i < 32; i += 8)
    dst[(size_t)(c0 + ty + i) * R + r0 + tx] = tile[tx][ty + i];
}

// ---------------------------------------------------------------------------
// bf16 -> bf16 batched transpose (for V): dst[z][c][r] = src[z][r][c]
// grid: (C/32, R/32, batch), block 256
// ---------------------------------------------------------------------------
__global__ void transpose_bf16(const bf16* __restrict__ src, bf16* __restrict__ dst,
                               int R, int C) {
  __shared__ bf16 tile[32][33];
  size_t bofs = (size_t)blockIdx.z * R * C;
  int c0 = blockIdx.x * 32, r0 = blockIdx.y * 32;
  int tx = threadIdx.x & 31, ty = threadIdx.x >> 5;
  for (int i = 0; i < 32; i += 8)
    tile[ty + i][tx] = src[bofs + (size_t)(r0 + ty + i) * C + c0 + tx];
  __syncthreads();
  for (int i = 0; i < 32; i += 8)
    dst[bofs + (size_t)(c0 + ty + i) * R + r0 + tx] = tile[tx][ty + i];
}

// ---------------------------------------------------------------------------
// rpe cumsum: cum[n][t] = sum_{u<=t} rpe[n][u]  (f32 in, f32 out). grid NH
// ---------------------------------------------------------------------------
__global__ void rpe_scan(const float* __restrict__ rpe, float* __restrict__ cum) {
  __shared__ float ssum[256];
  int n = blockIdx.x, t = threadIdx.x;
  float loc[8];
  float s = 0.f;
  int base = t * 8;
  for (int u = 0; u < 8; ++u) {
    loc[u] = rpe[n * S_ + base + u];
    s += loc[u];
  }
  ssum[t] = s;
  __syncthreads();
  float own = s;
  for (int off = 1; off < 256; off <<= 1) {
    float v = (t >= off) ? ssum[t - off] : 0.f;
    __syncthreads();
    ssum[t] += v;
    __syncthreads();
  }
  float run = ssum[t] - own;   // exclusive prefix of this thread's chunk
  for (int u = 0; u < 8; ++u) {
    run += loc[u];
    cum[n * S_ + base + u] = run;
  }
}

// ---------------------------------------------------------------------------
// GEMM: C[M x Nc] = A[M x 1024] * Bt[Nc x 1024]^T, bf16 in, f32 acc.
// 128x128 tile, BK=32, 256 threads (4 waves, 2x2 of 64x64).
// XOR-swizzled LDS (chunk c at slot c ^ ((row>>1)&3)) -> 2-way reads (free).
// MODE 0: scatter epilogue into q/k/v bf16 buffers ([b,n,s,d]);  Nc=3072
// MODE 1: f32 store to F0, row stride 1024;                      Nc=1024
// ---------------------------------------------------------------------------
template <int MODE>
__global__ __launch_bounds__(256, 2)
void gemm_bt(const bf16* __restrict__ A, const bf16* __restrict__ Bt,
             bf16* __restrict__ C0, bf16* __restrict__ C1, bf16* __restrict__ C2,
             float* __restrict__ F0) {
  __shared__ bf16 As[128 * 32] __attribute__((aligned(16)));
  __shared__ bf16 Bs[128 * 32] __attribute__((aligned(16)));
  const int tid = threadIdx.x, lane = tid & 63, w = tid >> 6;
  const int lr = lane & 15, lq = lane >> 4;
  const int m0 = blockIdx.y * 128, n0 = blockIdx.x * 128;
  const int wm = (w & 1) * 64, wn = (w >> 1) * 64;

  f32x4 acc[4][4] = {};

  for (int k0 = 0; k0 < 1024; k0 += 32) {
    __syncthreads();
    for (int t = 0; t < 2; ++t) {
      int c = (t * 4 + w) * 64 + lane;          // 16B-chunk id 0..511
      int row = c >> 2, ch = c & 3;
      int k8 = (ch ^ ((row >> 1) & 3)) * 8;     // swizzled source chunk
      async16(A + (size_t)(m0 + row) * 1024 + k0 + k8,
              (char*)As + (size_t)(t * 4 + w) * 1024 + lane * 16);
      async16(Bt + (size_t)(n0 + row) * 1024 + k0 + k8,
              (char*)Bs + (size_t)(t * 4 + w) * 1024 + lane * 16);
    }
    __syncthreads();
    bf16x8 af[4], bfr[4];
#pragma unroll
    for (int mt = 0; mt < 4; ++mt) {
      int row = wm + mt * 16 + lr;
      af[mt] = *(const bf16x8*)(As + row * 32 + ((lq ^ ((row >> 1) & 3)) << 3));
    }
#pragma unroll
    for (int nt = 0; nt < 4; ++nt) {
      int row = wn + nt * 16 + lr;
      bfr[nt] = *(const bf16x8*)(Bs + row * 32 + ((lq ^ ((row >> 1) & 3)) << 3));
    }
#pragma unroll
    for (int mt = 0; mt < 4; ++mt)
#pragma unroll
      for (int nt = 0; nt < 4; ++nt)
        acc[mt][nt] = MFMA16(af[mt], bfr[nt], acc[mt][nt]);
  }

  if (MODE == 0) {
    // col cN in [0,3072): m = cN>>10 (q/k/v), n = (cN>>6)&15, d = cN&63
#pragma unroll
    for (int nt = 0; nt < 4; ++nt) {
      int cN = n0 + wn + nt * 16 + lr;
      int mm = cN >> 10, nn = (cN >> 6) & 15, dd = cN & 63;
      bf16* dst = mm == 0 ? C0 : (mm == 1 ? C1 : C2);
#pragma unroll
      for (int mt = 0; mt < 4; ++mt)
#pragma unroll
        for (int r = 0; r < 4; ++r) {
          int rM = m0 + wm + mt * 16 + lq * 4 + r;   // b*S + s
          int bb = rM >> 11, ss = rM & 2047;
          dst[((size_t)(bb * NH + nn) * S_ + ss) * DH + dd] =
              __float2bfloat16(acc[mt][nt][r]);
        }
    }
  } else {
#pragma unroll
    for (int mt = 0; mt < 4; ++mt)
#pragma unroll
      for (int nt = 0; nt < 4; ++nt)
#pragma unroll
        for (int r = 0; r < 4; ++r) {
          int rM = m0 + wm + mt * 16 + lq * 4 + r;
          int cN = n0 + wn + nt * 16 + lr;
          F0[(size_t)rM * 1024 + cN] = acc[mt][nt][r];
        }
  }
}

// ---------------------------------------------------------------------------
// Flash attention, causal + cumulative rpe bias.
// q,k: [bn][S][D] bf16;  vt: [bn][D][S] bf16;  cum: [N][S] f32
// mix out: [b][s][n][d] bf16
// grid (16, B*N), block 256 (4 waves). Block does 64-row Q-tiles {bx, 31-bx}
// -> uniform 17 KV-tile iterations. LDS 34816 B -> 4 blocks/CU capacity,
// all 512 blocks resident, ~2/CU overlap.
// LDS map: [0,17408) Ps[64][136] bf16, aliasing Ks (128 rows x 8 swizzled
// 16B chunks = 16384 B); [17408,33792) Vs (64 rows x 16 swizzled chunks);
// [33792,34816) cumbuf[256] f32.
// ---------------------------------------------------------------------------
__global__ __launch_bounds__(256, 4)
void fa_kernel(const bf16* __restrict__ q, const bf16* __restrict__ k,
               const bf16* __restrict__ vt, const float* __restrict__ cum,
               bf16* __restrict__ mix) {
  __shared__ char smem[34816] __attribute__((aligned(16)));
  bf16* Ps = (bf16*)smem;                       // [64][136]
  float* cumbuf = (float*)(smem + 33792);       // [256]

  const int tid = threadIdx.x, lane = tid & 63, w = tid >> 6;  // w: 0..3
  const int lr = lane & 15, lq = lane >> 4;
  const int bn = blockIdx.y;
  const int n = bn & (NH - 1);
  const int b = bn >> 4;
  const float* cumn = cum + n * S_;

  for (int tt = 0; tt < 2; ++tt) {
    const int ti = (tt == 0) ? (int)blockIdx.x : 31 - (int)blockIdx.x;
    const int i0 = ti * 64;
    const int nj = (ti >> 1) + 1;     // KV tiles needed (128 cols each)

    // Q fragments for this wave's 16 rows (A-operand layout)
    const bf16* qbase = q + ((size_t)bn * S_ + i0 + w * 16) * DH;
    bf16x8 qf[2];
#pragma unroll
    for (int kt = 0; kt < 2; ++kt)
      qf[kt] = *(const bf16x8*)(qbase + lr * DH + kt * 32 + lq * 8);

    f32x4 oacc[4] = {};
    float m_i[4], l_i[4];
#pragma unroll
    for (int r = 0; r < 4; ++r) { m_i[r] = -1e30f; l_i[r] = 0.f; }

    for (int jt = 0; jt < nj; ++jt) {
      const int j0 = jt * 128;
      const bool diag = (jt == nj - 1);
      __syncthreads();   // prior P/V/cum reads done; regions free

      // stage K tile (swizzled: slot (row,c) holds global chunk c^(row&7))
      const char* ksrc = (const char*)(k + ((size_t)bn * S_ + j0) * DH);
#pragma unroll
      for (int t = 0; t < 4; ++t) {
        int cb = t * 4 + w;
        int row = cb * 8 + (lane >> 3);
        int cs = (lane & 7) ^ (row & 7);
        async16(ksrc + row * 128 + cs * 16, smem + cb * 1024 + lane * 16);
      }
      // stage Vt tile (swizzled: slot (row,c) holds global chunk c^(row&15))
      const char* vsrc = (const char*)(vt + (size_t)bn * DH * S_);
#pragma unroll
      for (int t = 0; t < 4; ++t) {
        int cb = t * 4 + w;
        int row = cb * 4 + (lane >> 4);          // d index 0..63
        int cs = (lane & 15) ^ (row & 15);
        async16(vsrc + (size_t)row * (S_ * 2) + j0 * 2 + cs * 16,
                smem + 17408 + cb * 1024 + lane * 16);
      }
      // stage cum window: cumbuf[t] = cumn[clamp(i0-j0-127+t)]
      {
        int src = i0 - j0 - 127 + tid;
        src = src < 0 ? 0 : (src > S_ - 1 ? S_ - 1 : src);
        cumbuf[tid] = cumn[src];
      }
      __syncthreads();   // staging complete

      // S = Q K^T  (wave's 16 rows x 128 cols)
      f32x4 sa[8] = {};
#pragma unroll
      for (int kt = 0; kt < 2; ++kt)
#pragma unroll
        for (int nt = 0; nt < 8; ++nt) {
          int krow = nt * 16 + lr;
          bf16x8 kf = *(const bf16x8*)(smem + krow * 128 +
                          (((kt * 4 + lq) ^ (krow & 7)) << 4));
          sa[nt] = MFMA16(qf[kt], kf, sa[nt]);
        }
      __syncthreads();   // all Ks reads done before P overwrites the region

      // scale + bias (+ causal mask on diagonal tile); track row maxes
      const int rbase = w * 16 + lq * 4;
      const int doff = i0 - j0;     // 0 or 64 on diagonal tile
      float rmax[4] = {-1e30f, -1e30f, -1e30f, -1e30f};
      if (!diag) {
#pragma unroll
        for (int nt = 0; nt < 8; ++nt)
#pragma unroll
          for (int r = 0; r < 4; ++r) {
            int rel = rbase + r - nt * 16 - lr;
            float val = sa[nt][r] * SCALE + cumbuf[127 + rel];
            sa[nt][r] = val;
            rmax[r] = fmaxf(rmax[r], val);
          }
      } else {
#pragma unroll
        for (int nt = 0; nt < 8; ++nt)
#pragma unroll
          for (int r = 0; r < 4; ++r) {
            int rel = rbase + r - nt * 16 - lr;
            float val = (doff + rel >= 0) ? sa[nt][r] * SCALE + cumbuf[127 + rel]
                                          : -1e30f;
            sa[nt][r] = val;
            rmax[r] = fmaxf(rmax[r], val);
          }
      }
      // online softmax per row (row owned by 16 consecutive lanes)
#pragma unroll
      for (int r = 0; r < 4; ++r) {
        float mx = rmax[r];
        mx = fmaxf(mx, __shfl_xor(mx, 1));
        mx = fmaxf(mx, __shfl_xor(mx, 2));
        mx = fmaxf(mx, __shfl_xor(mx, 4));
        mx = fmaxf(mx, __shfl_xor(mx, 8));
        float newm = fmaxf(m_i[r], mx);
        float al = __expf(m_i[r] - newm);
        m_i[r] = newm;
        float rs = 0.f;
#pragma unroll
        for (int nt = 0; nt < 8; ++nt) {
          float p = __expf(sa[nt][r] - newm);
          sa[nt][r] = p;
          rs += p;
        }
        rs += __shfl_xor(rs, 1);
        rs += __shfl_xor(rs, 2);
        rs += __shfl_xor(rs, 4);
        rs += __shfl_xor(rs, 8);
        l_i[r] = l_i[r] * al + rs;
#pragma unroll
        for (int dt = 0; dt < 4; ++dt) oacc[dt][r] *= al;
      }
      // write P (bf16) to this wave's private 16 rows
#pragma unroll
      for (int nt = 0; nt < 8; ++nt)
#pragma unroll
        for (int r = 0; r < 4; ++r)
          Ps[(w * 16 + lq * 4 + r) * 136 + nt * 16 + lr] =
              __float2bfloat16(sa[nt][r]);

      // O += P V (wave-private P rows; in-wave DS ordering suffices)
#pragma unroll
      for (int kt2 = 0; kt2 < 4; ++kt2) {
        bf16x8 pf = *(const bf16x8*)(Ps + (w * 16 + lr) * 136 + kt2 * 32 + lq * 8);
#pragma unroll
        for (int dt = 0; dt < 4; ++dt) {
          int vrow = dt * 16 + lr;
          bf16x8 vf = *(const bf16x8*)(smem + 17408 + vrow * 256 +
                          (((kt2 * 4 + lq) ^ (vrow & 15)) << 4));
          oacc[dt] = MFMA16(pf, vf, oacc[dt]);
        }
      }
    }

    // epilogue: mix[b][s][n][d]
#pragma unroll
    for (int dt = 0; dt < 4; ++dt)
#pragma unroll
      for (int r = 0; r < 4; ++r) {
        int i = i0 + w * 16 + lq * 4 + r;
        int d = dt * 16 + lr;
        mix[((size_t)(b * S_ + i) * NH + n) * DH + d] =
            __float2bfloat16(oacc[dt][r] / l_i[r]);
      }
  }
}

// ---------------------------------------------------------------------------
extern "C" void kernel_launch(void* const* d_in, const int* in_sizes, int n_in,
                              void* d_out, int out_size, void* d_ws, size_t ws_size,
                              hipStream_t stream) {
  const float* x     = (const float*)d_in[0];   // [B,S,H] f32
  const float* qkv   = (const float*)d_in[1];   // [H,3,N,D] f32 == [1024][3072]
  const float* out_w = (const float*)d_in[2];   // [N,D,H] f32   == [1024][1024]
  const float* rpe   = (const float*)d_in[3];   // [N,S] f32
  float* out = (float*)d_out;                   // [B,S,H] f32

  char* ws = (char*)d_ws;
  bf16* qkvT  = (bf16*)(ws + 0);          // [3072][1024] bf16   6291456 B
  bf16* outwT = (bf16*)(ws + 6291456);    // [1024][1024] bf16   2097152 B
  bf16* xb    = (bf16*)(ws + 8388608);    // [4096][1024] bf16   8388608 B
  bf16* qb    = (bf16*)(ws + 16777216);   // [bn][S][D]          8388608 B
  bf16* kb    = (bf16*)(ws + 25165824);   // [bn][S][D]          8388608 B
  bf16* vb    = (bf16*)(ws + 33554432);   // [bn][S][D]          8388608 B
  bf16* vtb   = (bf16*)(ws + 41943040);   // [bn][D][S]          8388608 B
  bf16* mixb  = (bf16*)(ws + 50331648);   // [b][s][n][d]        8388608 B
  float* cum  = (float*)(ws + 58720256);  // [N][S] f32           131072 B

  // 1. convert x; pre-transpose+convert weights
  convert_f32_bf16<<<4096, 256, 0, stream>>>(x, xb, 4096 * 1024);
  transpose_f32_bf16<<<dim3(3072 / 32, 1024 / 32), 256, 0, stream>>>(qkv, qkvT, 1024, 3072);
  transpose_f32_bf16<<<dim3(1024 / 32, 1024 / 32), 256, 0, stream>>>(out_w, outwT, 1024, 1024);
  // 2. rpe cumsum
  rpe_scan<<<NH, 256, 0, stream>>>(rpe, cum);
  // 3. QKV projection
  gemm_bt<0><<<dim3(3072 / 128, 4096 / 128), 256, 0, stream>>>(xb, qkvT, qb, kb, vb, nullptr);
  // 4. transpose V per (b,n)
  transpose_bf16<<<dim3(DH / 32, S_ / 32, B_ * NH), 256, 0, stream>>>(vb, vtb, S_, DH);
  // 5. attention
  fa_kernel<<<dim3(16, B_ * NH), 256, 0, stream>>>(qb, kb, vtb, cum, mixb);
  // 6. output projection (f32 out)
  gemm_bt<1><<<dim3(1024 / 128, 4096 / 128), 256, 0, stream>>>(mixb, outwT, nullptr, nullptr, nullptr, out);
}

// Round 4
// 214.647 us; speedup vs baseline: 1.3324x; 1.2495x over previous
//
#include <hip/hip_runtime.h>
#include <hip/hip_bf16.h>
#include <cstdint>
#include <cstddef>

// Problem constants
#define B_   2
#define S_   2048
#define H_   1024
#define NH   16
#define DH   64
#define SCALE 0.125f   // D^-0.5

typedef __hip_bfloat16 bf16;
typedef short bf16x8 __attribute__((ext_vector_type(8)));   // 8 bf16 in 4 VGPRs
typedef float f32x4 __attribute__((ext_vector_type(4)));

#define MFMA16(a, b, c) __builtin_amdgcn_mfma_f32_16x16x32_bf16((a), (b), (c), 0, 0, 0)

__device__ __forceinline__ void async16(const void* g, void* l) {
  __builtin_amdgcn_global_load_lds(
      (const __attribute__((address_space(1))) void*)g,
      (__attribute__((address_space(3))) void*)l,
      16, 0, 0);
}

// ---------------------------------------------------------------------------
// f32 -> bf16 elementwise convert (4 elems/thread)
// ---------------------------------------------------------------------------
__global__ void convert_f32_bf16(const float* __restrict__ src, bf16* __restrict__ dst,
                                 int n) {
  int i = (blockIdx.x * 256 + threadIdx.x) * 4;
  if (i + 3 < n) {
    float4 v = *(const float4*)(src + i);
    dst[i + 0] = __float2bfloat16(v.x);
    dst[i + 1] = __float2bfloat16(v.y);
    dst[i + 2] = __float2bfloat16(v.z);
    dst[i + 3] = __float2bfloat16(v.w);
  }
}

// ---------------------------------------------------------------------------
// f32 -> bf16 transpose: dst[c][r] = (bf16)src[r][c]. grid (C/32, R/32), blk 256
// ---------------------------------------------------------------------------
__global__ void transpose_f32_bf16(const float* __restrict__ src, bf16* __restrict__ dst,
                                   int R, int C) {
  __shared__ bf16 tile[32][33];
  int c0 = blockIdx.x * 32, r0 = blockIdx.y * 32;
  int tx = threadIdx.x & 31, ty = threadIdx.x >> 5;   // 32 x 8
  for (int i = 0; i < 32; i += 8)
    tile[ty + i][tx] = __float2bfloat16(src[(size_t)(r0 + ty + i) * C + c0 + tx]);
  __syncthreads();
  for (int i = 0; i < 32; i += 8)
    dst[(size_t)(c0 + ty + i) * R + r0 + tx] = tile[tx][ty + i];
}

// ---------------------------------------------------------------------------
// rpe cumsum: cum[n][t] = sum_{u<=t} rpe[n][u]  (f32 in, f32 out). grid NH
// ---------------------------------------------------------------------------
__global__ void rpe_scan(const float* __restrict__ rpe, float* __restrict__ cum) {
  __shared__ float ssum[256];
  int n = blockIdx.x, t = threadIdx.x;
  float loc[8];
  float s = 0.f;
  int base = t * 8;
  for (int u = 0; u < 8; ++u) {
    loc[u] = rpe[n * S_ + base + u];
    s += loc[u];
  }
  ssum[t] = s;
  __syncthreads();
  float own = s;
  for (int off = 1; off < 256; off <<= 1) {
    float v = (t >= off) ? ssum[t - off] : 0.f;
    __syncthreads();
    ssum[t] += v;
    __syncthreads();
  }
  float run = ssum[t] - own;   // exclusive prefix of this thread's chunk
  for (int u = 0; u < 8; ++u) {
    run += loc[u];
    cum[n * S_ + base + u] = run;
  }
}

// ---------------------------------------------------------------------------
// GEMM: C[M x Nc] = A[M x 1024] * Bt[Nc x 1024]^T, bf16 in, f32 acc.
// 128x128 tile, BK=32, 256 threads (4 waves, 2x2 of 64x64).
// XOR-swizzled LDS (chunk c at slot c ^ ((row>>1)&3)) -> 2-way reads (free).
// MODE 0: scatter into q ([bn,s,d]), k ([bn,s,d]), V TRANSPOSED ([bn,d,s]).
// MODE 1: f32 store to F0, row stride 1024;  Nc=1024
// ---------------------------------------------------------------------------
template <int MODE>
__global__ __launch_bounds__(256, 2)
void gemm_bt(const bf16* __restrict__ A, const bf16* __restrict__ Bt,
             bf16* __restrict__ C0, bf16* __restrict__ C1, bf16* __restrict__ C2,
             float* __restrict__ F0) {
  __shared__ bf16 As[128 * 32] __attribute__((aligned(16)));
  __shared__ bf16 Bs[128 * 32] __attribute__((aligned(16)));
  const int tid = threadIdx.x, lane = tid & 63, w = tid >> 6;
  const int lr = lane & 15, lq = lane >> 4;
  const int m0 = blockIdx.y * 128, n0 = blockIdx.x * 128;
  const int wm = (w & 1) * 64, wn = (w >> 1) * 64;

  f32x4 acc[4][4] = {};

  for (int k0 = 0; k0 < 1024; k0 += 32) {
    __syncthreads();
    for (int t = 0; t < 2; ++t) {
      int c = (t * 4 + w) * 64 + lane;          // 16B-chunk id 0..511
      int row = c >> 2, ch = c & 3;
      int k8 = (ch ^ ((row >> 1) & 3)) * 8;     // swizzled source chunk
      async16(A + (size_t)(m0 + row) * 1024 + k0 + k8,
              (char*)As + (size_t)(t * 4 + w) * 1024 + lane * 16);
      async16(Bt + (size_t)(n0 + row) * 1024 + k0 + k8,
              (char*)Bs + (size_t)(t * 4 + w) * 1024 + lane * 16);
    }
    __syncthreads();
    bf16x8 af[4], bfr[4];
#pragma unroll
    for (int mt = 0; mt < 4; ++mt) {
      int row = wm + mt * 16 + lr;
      af[mt] = *(const bf16x8*)(As + row * 32 + ((lq ^ ((row >> 1) & 3)) << 3));
    }
#pragma unroll
    for (int nt = 0; nt < 4; ++nt) {
      int row = wn + nt * 16 + lr;
      bfr[nt] = *(const bf16x8*)(Bs + row * 32 + ((lq ^ ((row >> 1) & 3)) << 3));
    }
#pragma unroll
    for (int mt = 0; mt < 4; ++mt)
#pragma unroll
      for (int nt = 0; nt < 4; ++nt)
        acc[mt][nt] = MFMA16(af[mt], bfr[nt], acc[mt][nt]);
  }

  if (MODE == 0) {
    // col cN in [0,3072): m = cN>>10 (q/k/v), n = (cN>>6)&15, d = cN&63
#pragma unroll
    for (int nt = 0; nt < 4; ++nt) {
      int cN = n0 + wn + nt * 16 + lr;
      int mm = cN >> 10, nn = (cN >> 6) & 15, dd = cN & 63;
      if (mm < 2) {
        bf16* dst = mm == 0 ? C0 : C1;
#pragma unroll
        for (int mt = 0; mt < 4; ++mt)
#pragma unroll
          for (int r = 0; r < 4; ++r) {
            int rM = m0 + wm + mt * 16 + lq * 4 + r;   // b*S + s
            int bb = rM >> 11, ss = rM & 2047;
            dst[((size_t)(bb * NH + nn) * S_ + ss) * DH + dd] =
                __float2bfloat16(acc[mt][nt][r]);
          }
      } else {
        // V: store transposed [bn][d][s]
#pragma unroll
        for (int mt = 0; mt < 4; ++mt)
#pragma unroll
          for (int r = 0; r < 4; ++r) {
            int rM = m0 + wm + mt * 16 + lq * 4 + r;
            int bb = rM >> 11, ss = rM & 2047;
            C2[((size_t)(bb * NH + nn) * DH + dd) * S_ + ss] =
                __float2bfloat16(acc[mt][nt][r]);
          }
      }
    }
  } else {
#pragma unroll
    for (int mt = 0; mt < 4; ++mt)
#pragma unroll
      for (int nt = 0; nt < 4; ++nt)
#pragma unroll
        for (int r = 0; r < 4; ++r) {
          int rM = m0 + wm + mt * 16 + lq * 4 + r;
          int cN = n0 + wn + nt * 16 + lr;
          F0[(size_t)rM * 1024 + cN] = acc[mt][nt][r];
        }
  }
}

// ---------------------------------------------------------------------------
// Flash attention, causal + cumulative rpe bias.
// q,k: [bn][S][D] bf16;  vt: [bn][D][S] bf16;  cum: [N][S] f32
// mix out: [b][s][n][d] bf16
// 1D grid 1024, block 256 (4 waves). Decode: xcd=L&7 pins 4 heads per XCD
// (KV working set 2 MB < 4 MB XCD-L2); ti descends with L (big blocks first).
// One 64-row Q-tile per block; nj=(ti>>1)+1 KV-tile iters.
// S^T trick: compute S^T = K*Q^T so each lane owns ONE softmax row (i=lane&15,
// j contiguous in regs) -> b64 P-writes, 2-shuffle reductions.
// LDS map: [0,17408) Ps[64][136] bf16 (aliases Ks: 128 rows x 8 swizzled 16B
// chunks = 16384 B + 1 KB gap); [17408,33792) Vs; [33792,34816) cumbuf[256].
// ---------------------------------------------------------------------------
__global__ __launch_bounds__(256, 4)
void fa_kernel(const bf16* __restrict__ q, const bf16* __restrict__ k,
               const bf16* __restrict__ vt, const float* __restrict__ cum,
               bf16* __restrict__ mix) {
  __shared__ char smem[34816] __attribute__((aligned(16)));
  bf16* Ps = (bf16*)smem;                       // [64][136]
  float* cumbuf = (float*)(smem + 33792);       // [256]

  const int tid = threadIdx.x, lane = tid & 63, w = tid >> 6;  // w: 0..3
  const int lr = lane & 15, lq = lane >> 4;

  const int L = blockIdx.x;
  const int xcd = L & 7, slot = L >> 3;
  const int bn = xcd + 8 * (slot >> 5);         // 4 heads per XCD
  const int ti = 31 - (slot & 31);              // descending work
  const int n = bn & (NH - 1);
  const int b = bn >> 4;
  const float* cumn = cum + n * S_;

  const int i0 = ti * 64;
  const int nj = (ti >> 1) + 1;                 // KV tiles (128 cols each)

  // Q fragments (B-operand for S^T = K*Q^T): lane n=lr reads Q row lr
  const bf16* qbase = q + ((size_t)bn * S_ + i0 + w * 16) * DH;
  bf16x8 qf[2];
#pragma unroll
  for (int kt = 0; kt < 2; ++kt)
    qf[kt] = *(const bf16x8*)(qbase + lr * DH + kt * 32 + lq * 8);

  f32x4 oacc[4] = {};
  float m_i = -1e30f, l_i = 0.f;                // scalar: this lane's row i=lr
  const int iloc = w * 16 + lr;

  for (int jt = 0; jt < nj; ++jt) {
    const int j0 = jt * 128;
    const bool diag = (jt == nj - 1);
    __syncthreads();   // prior P/V/cum reads done; regions free

    // stage K tile (swizzled: slot (row,c) holds global chunk c^(row&7))
    const char* ksrc = (const char*)(k + ((size_t)bn * S_ + j0) * DH);
#pragma unroll
    for (int t = 0; t < 4; ++t) {
      int cb = t * 4 + w;
      int row = cb * 8 + (lane >> 3);
      int cs = (lane & 7) ^ (row & 7);
      async16(ksrc + row * 128 + cs * 16, smem + cb * 1024 + lane * 16);
    }
    // stage Vt tile (swizzled: slot (row,c) holds global chunk c^(row&15))
    const char* vsrc = (const char*)(vt + (size_t)bn * DH * S_);
#pragma unroll
    for (int t = 0; t < 4; ++t) {
      int cb = t * 4 + w;
      int row = cb * 4 + (lane >> 4);          // d index 0..63
      int cs = (lane & 15) ^ (row & 15);
      async16(vsrc + (size_t)row * (S_ * 2) + j0 * 2 + cs * 16,
              smem + 17408 + cb * 1024 + lane * 16);
    }
    // stage cum window: cumbuf[t] = cumn[clamp(i0-j0-127+t)]
    {
      int src = i0 - j0 - 127 + tid;
      src = src < 0 ? 0 : (src > S_ - 1 ? S_ - 1 : src);
      cumbuf[tid] = cumn[src];
    }
    __syncthreads();   // staging complete

    // S^T = K * Q^T: sa[nt][r] = S[i=i0+iloc][j = j0 + nt*16 + lq*4 + r]
    f32x4 sa[8] = {};
#pragma unroll
    for (int kt = 0; kt < 2; ++kt)
#pragma unroll
      for (int nt = 0; nt < 8; ++nt) {
        int krow = nt * 16 + lr;
        bf16x8 kf = *(const bf16x8*)(smem + krow * 128 +
                        (((kt * 4 + lq) ^ (krow & 7)) << 4));
        sa[nt] = MFMA16(kf, qf[kt], sa[nt]);
      }
    __syncthreads();   // all Ks reads done before P overwrites the region

    // scale + bias (+ causal mask on diagonal tile); single row per lane
    const int doff = i0 - j0;     // 0 or 64 on diagonal tile
    float rmax = -1e30f;
    if (!diag) {
#pragma unroll
      for (int nt = 0; nt < 8; ++nt)
#pragma unroll
        for (int r = 0; r < 4; ++r) {
          int rel = iloc - nt * 16 - lq * 4 - r;
          float val = sa[nt][r] * SCALE + cumbuf[127 + rel];
          sa[nt][r] = val;
          rmax = fmaxf(rmax, val);
        }
    } else {
#pragma unroll
      for (int nt = 0; nt < 8; ++nt)
#pragma unroll
        for (int r = 0; r < 4; ++r) {
          int rel = iloc - nt * 16 - lq * 4 - r;
          float val = (doff + rel >= 0) ? sa[nt][r] * SCALE + cumbuf[127 + rel]
                                        : -1e30f;
          sa[nt][r] = val;
          rmax = fmaxf(rmax, val);
        }
    }
    // online softmax: combine quads (lanes lr, lr+16, lr+32, lr+48 share row)
    float mx = fmaxf(rmax, __shfl_xor(rmax, 16));
    mx = fmaxf(mx, __shfl_xor(mx, 32));
    float newm = fmaxf(m_i, mx);
    float al = __expf(m_i - newm);
    m_i = newm;
    float rs = 0.f;
#pragma unroll
    for (int nt = 0; nt < 8; ++nt)
#pragma unroll
      for (int r = 0; r < 4; ++r) {
        float p = __expf(sa[nt][r] - newm);
        sa[nt][r] = p;
        rs += p;
      }
    rs += __shfl_xor(rs, 16);
    rs += __shfl_xor(rs, 32);
    l_i = l_i * al + rs;
    // rescale O (O rows indexed by lq*4+r; alpha lives at lane lq*4+r)
    float alr[4];
#pragma unroll
    for (int r = 0; r < 4; ++r) alr[r] = __shfl(al, lq * 4 + r);
#pragma unroll
    for (int dt = 0; dt < 4; ++dt)
#pragma unroll
      for (int r = 0; r < 4; ++r) oacc[dt][r] *= alr[r];

    // write P row iloc: 4 consecutive j per reg quad -> b64 stores
#pragma unroll
    for (int nt = 0; nt < 8; ++nt) {
      bf16 pk[4];
#pragma unroll
      for (int r = 0; r < 4; ++r) pk[r] = __float2bfloat16(sa[nt][r]);
      *(uint64_t*)(Ps + iloc * 136 + nt * 16 + lq * 4) = *(const uint64_t*)pk;
    }

    // O += P V (wave-private P rows; in-wave DS ordering suffices)
#pragma unroll
    for (int kt2 = 0; kt2 < 4; ++kt2) {
      bf16x8 pf = *(const bf16x8*)(Ps + (w * 16 + lr) * 136 + kt2 * 32 + lq * 8);
#pragma unroll
      for (int dt = 0; dt < 4; ++dt) {
        int vrow = dt * 16 + lr;
        bf16x8 vf = *(const bf16x8*)(smem + 17408 + vrow * 256 +
                        (((kt2 * 4 + lq) ^ (vrow & 15)) << 4));
        oacc[dt] = MFMA16(pf, vf, oacc[dt]);
      }
    }
  }

  // epilogue: mix[b][s][n][d];  l for O-row lq*4+r lives at lane lq*4+r
  float lr4[4];
#pragma unroll
  for (int r = 0; r < 4; ++r) lr4[r] = __shfl(l_i, lq * 4 + r);
#pragma unroll
  for (int dt = 0; dt < 4; ++dt)
#pragma unroll
    for (int r = 0; r < 4; ++r) {
      int i = i0 + w * 16 + lq * 4 + r;
      int d = dt * 16 + lr;
      mix[((size_t)(b * S_ + i) * NH + n) * DH + d] =
          __float2bfloat16(oacc[dt][r] / lr4[r]);
    }
}

// ---------------------------------------------------------------------------
extern "C" void kernel_launch(void* const* d_in, const int* in_sizes, int n_in,
                              void* d_out, int out_size, void* d_ws, size_t ws_size,
                              hipStream_t stream) {
  const float* x     = (const float*)d_in[0];   // [B,S,H] f32
  const float* qkv   = (const float*)d_in[1];   // [H,3,N,D] f32 == [1024][3072]
  const float* out_w = (const float*)d_in[2];   // [N,D,H] f32   == [1024][1024]
  const float* rpe   = (const float*)d_in[3];   // [N,S] f32
  float* out = (float*)d_out;                   // [B,S,H] f32

  char* ws = (char*)d_ws;
  bf16* qkvT  = (bf16*)(ws + 0);          // [3072][1024] bf16   6291456 B
  bf16* outwT = (bf16*)(ws + 6291456);    // [1024][1024] bf16   2097152 B
  bf16* xb    = (bf16*)(ws + 8388608);    // [4096][1024] bf16   8388608 B
  bf16* qb    = (bf16*)(ws + 16777216);   // [bn][S][D]          8388608 B
  bf16* kb    = (bf16*)(ws + 25165824);   // [bn][S][D]          8388608 B
  bf16* vtb   = (bf16*)(ws + 33554432);   // [bn][D][S]          8388608 B
  bf16* mixb  = (bf16*)(ws + 41943040);   // [b][s][n][d]        8388608 B
  float* cum  = (float*)(ws + 50331648);  // [N][S] f32           131072 B

  // 1. convert x; pre-transpose+convert weights
  convert_f32_bf16<<<4096, 256, 0, stream>>>(x, xb, 4096 * 1024);
  transpose_f32_bf16<<<dim3(3072 / 32, 1024 / 32), 256, 0, stream>>>(qkv, qkvT, 1024, 3072);
  transpose_f32_bf16<<<dim3(1024 / 32, 1024 / 32), 256, 0, stream>>>(out_w, outwT, 1024, 1024);
  // 2. rpe cumsum
  rpe_scan<<<NH, 256, 0, stream>>>(rpe, cum);
  // 3. QKV projection (V written pre-transposed)
  gemm_bt<0><<<dim3(3072 / 128, 4096 / 128), 256, 0, stream>>>(xb, qkvT, qb, kb, vtb, nullptr);
  // 4. attention
  fa_kernel<<<1024, 256, 0, stream>>>(qb, kb, vtb, cum, mixb);
  // 5. output projection (f32 out)
  gemm_bt<1><<<dim3(1024 / 128, 4096 / 128), 256, 0, stream>>>(mixb, outwT, nullptr, nullptr, nullptr, out);
}

// Round 5
// 200.226 us; speedup vs baseline: 1.4284x; 1.0720x over previous
//
#include <hip/hip_runtime.h>
#include <hip/hip_bf16.h>
#include <cstdint>
#include <cstddef>

// Problem constants
#define B_   2
#define S_   2048
#define H_   1024
#define NH   16
#define DH   64
#define SCALE 0.125f   // D^-0.5

typedef __hip_bfloat16 bf16;
typedef short bf16x8 __attribute__((ext_vector_type(8)));   // 8 bf16 in 4 VGPRs
typedef float f32x4 __attribute__((ext_vector_type(4)));

#define MFMA16(a, b, c) __builtin_amdgcn_mfma_f32_16x16x32_bf16((a), (b), (c), 0, 0, 0)

__device__ __forceinline__ void async16(const void* g, void* l) {
  __builtin_amdgcn_global_load_lds(
      (const __attribute__((address_space(1))) void*)g,
      (__attribute__((address_space(3))) void*)l,
      16, 0, 0);
}

// ---------------------------------------------------------------------------
// f32 -> bf16 elementwise convert (4 elems/thread)
// ---------------------------------------------------------------------------
__global__ void convert_f32_bf16(const float* __restrict__ src, bf16* __restrict__ dst,
                                 int n) {
  int i = (blockIdx.x * 256 + threadIdx.x) * 4;
  if (i + 3 < n) {
    float4 v = *(const float4*)(src + i);
    dst[i + 0] = __float2bfloat16(v.x);
    dst[i + 1] = __float2bfloat16(v.y);
    dst[i + 2] = __float2bfloat16(v.z);
    dst[i + 3] = __float2bfloat16(v.w);
  }
}

// ---------------------------------------------------------------------------
// f32 -> bf16 transpose: dst[c][r] = (bf16)src[r][c]. grid (C/32, R/32), blk 256
// ---------------------------------------------------------------------------
__global__ void transpose_f32_bf16(const float* __restrict__ src, bf16* __restrict__ dst,
                                   int R, int C) {
  __shared__ bf16 tile[32][33];
  int c0 = blockIdx.x * 32, r0 = blockIdx.y * 32;
  int tx = threadIdx.x & 31, ty = threadIdx.x >> 5;   // 32 x 8
  for (int i = 0; i < 32; i += 8)
    tile[ty + i][tx] = __float2bfloat16(src[(size_t)(r0 + ty + i) * C + c0 + tx]);
  __syncthreads();
  for (int i = 0; i < 32; i += 8)
    dst[(size_t)(c0 + ty + i) * R + r0 + tx] = tile[tx][ty + i];
}

// ---------------------------------------------------------------------------
// rpe cumsum: cum[n][t] = sum_{u<=t} rpe[n][u]  (f32 in, f32 out). grid NH
// ---------------------------------------------------------------------------
__global__ void rpe_scan(const float* __restrict__ rpe, float* __restrict__ cum) {
  __shared__ float ssum[256];
  int n = blockIdx.x, t = threadIdx.x;
  float loc[8];
  float s = 0.f;
  int base = t * 8;
  for (int u = 0; u < 8; ++u) {
    loc[u] = rpe[n * S_ + base + u];
    s += loc[u];
  }
  ssum[t] = s;
  __syncthreads();
  float own = s;
  for (int off = 1; off < 256; off <<= 1) {
    float v = (t >= off) ? ssum[t - off] : 0.f;
    __syncthreads();
    ssum[t] += v;
    __syncthreads();
  }
  float run = ssum[t] - own;   // exclusive prefix of this thread's chunk
  for (int u = 0; u < 8; ++u) {
    run += loc[u];
    cum[n * S_ + base + u] = run;
  }
}

// ---------------------------------------------------------------------------
// GEMM: C[M x Nc] = A[M x 1024] * Bt[Nc x 1024]^T, bf16 in, f32 acc.
// 128x128 tile, BK=32, 256 threads (4 waves, 2x2 of 64x64).
// XOR-swizzled LDS (chunk c at slot c ^ ((row>>1)&3)) -> 2-way reads (free).
// MODE 0: epilogue re-layouts each wave's 64x64 tile through wave-private LDS
//   (no barrier needed for readback) then b128 stores: q,k as [bn][s][d],
//   V TRANSPOSED as [bn][d][s]. Per-wave col span is 64-aligned so the
//   q/k/v select (mm) and head (nn) are constant per wave.
// MODE 1: f32 store to F0, row stride 1024;  Nc=1024
// ---------------------------------------------------------------------------
template <int MODE>
__global__ __launch_bounds__(256, 2)
void gemm_bt(const bf16* __restrict__ A, const bf16* __restrict__ Bt,
             bf16* __restrict__ C0, bf16* __restrict__ C1, bf16* __restrict__ C2,
             float* __restrict__ F0) {
  __shared__ char smem[MODE == 0 ? 36864 : 16384] __attribute__((aligned(16)));
  bf16* As = (bf16*)smem;              // [128*32]
  bf16* Bs = (bf16*)(smem + 8192);     // [128*32]
  const int tid = threadIdx.x, lane = tid & 63, w = tid >> 6;
  const int lr = lane & 15, lq = lane >> 4;
  const int m0 = blockIdx.y * 128, n0 = blockIdx.x * 128;
  const int wm = (w & 1) * 64, wn = (w >> 1) * 64;

  f32x4 acc[4][4] = {};

  for (int k0 = 0; k0 < 1024; k0 += 32) {
    __syncthreads();
    for (int t = 0; t < 2; ++t) {
      int c = (t * 4 + w) * 64 + lane;          // 16B-chunk id 0..511
      int row = c >> 2, ch = c & 3;
      int k8 = (ch ^ ((row >> 1) & 3)) * 8;     // swizzled source chunk
      async16(A + (size_t)(m0 + row) * 1024 + k0 + k8,
              (char*)As + (size_t)(t * 4 + w) * 1024 + lane * 16);
      async16(Bt + (size_t)(n0 + row) * 1024 + k0 + k8,
              (char*)Bs + (size_t)(t * 4 + w) * 1024 + lane * 16);
    }
    __syncthreads();
    bf16x8 af[4], bfr[4];
#pragma unroll
    for (int mt = 0; mt < 4; ++mt) {
      int row = wm + mt * 16 + lr;
      af[mt] = *(const bf16x8*)(As + row * 32 + ((lq ^ ((row >> 1) & 3)) << 3));
    }
#pragma unroll
    for (int nt = 0; nt < 4; ++nt) {
      int row = wn + nt * 16 + lr;
      bfr[nt] = *(const bf16x8*)(Bs + row * 32 + ((lq ^ ((row >> 1) & 3)) << 3));
    }
#pragma unroll
    for (int mt = 0; mt < 4; ++mt)
#pragma unroll
      for (int nt = 0; nt < 4; ++nt)
        acc[mt][nt] = MFMA16(af[mt], bfr[nt], acc[mt][nt]);
  }

  if (MODE == 0) {
    __syncthreads();   // all As/Bs reads done; reuse LDS for epilogue tiles
    bf16* E = (bf16*)smem + w * (64 * 72);   // wave-private [64][72]
    const int cbase = n0 + wn;               // 64-aligned
    const int mm = cbase >> 10, nn = (cbase >> 6) & 15;
    const int bb = (m0 + wm) >> 11;
    const int sbase = (m0 + wm) & 2047;
    if (mm < 2) {
      // write acc as [s][d] into E
#pragma unroll
      for (int mt = 0; mt < 4; ++mt)
#pragma unroll
        for (int nt = 0; nt < 4; ++nt)
#pragma unroll
          for (int r = 0; r < 4; ++r)
            E[(mt * 16 + lq * 4 + r) * 72 + nt * 16 + lr] =
                __float2bfloat16(acc[mt][nt][r]);
      // wave-private readback (in-wave lgkm ordering), b128 stores
      bf16* dst = (mm == 0 ? C0 : C1) +
                  ((size_t)(bb * NH + nn) * S_ + sbase) * DH;
#pragma unroll
      for (int it = 0; it < 8; ++it) {
        int c = it * 64 + lane;
        int rw = c >> 3, c8 = c & 7;
        *(uint4*)(dst + (size_t)rw * DH + c8 * 8) =
            *(const uint4*)(E + rw * 72 + c8 * 8);
      }
    } else {
      // V: write acc as [d][s] into E
#pragma unroll
      for (int mt = 0; mt < 4; ++mt)
#pragma unroll
        for (int nt = 0; nt < 4; ++nt)
#pragma unroll
          for (int r = 0; r < 4; ++r)
            E[(nt * 16 + lr) * 72 + mt * 16 + lq * 4 + r] =
                __float2bfloat16(acc[mt][nt][r]);
      bf16* dst = C2 + (size_t)(bb * NH + nn) * DH * S_;
#pragma unroll
      for (int it = 0; it < 8; ++it) {
        int c = it * 64 + lane;
        int dr = c >> 3, c8 = c & 7;
        *(uint4*)(dst + (size_t)dr * S_ + sbase + c8 * 8) =
            *(const uint4*)(E + dr * 72 + c8 * 8);
      }
    }
  } else {
#pragma unroll
    for (int mt = 0; mt < 4; ++mt)
#pragma unroll
      for (int nt = 0; nt < 4; ++nt)
#pragma unroll
        for (int r = 0; r < 4; ++r) {
          int rM = m0 + wm + mt * 16 + lq * 4 + r;
          int cN = n0 + wn + nt * 16 + lr;
          F0[(size_t)rM * 1024 + cN] = acc[mt][nt][r];
        }
  }
}

// ---------------------------------------------------------------------------
// Flash attention, causal + cumulative rpe bias.
// q,k: [bn][S][D] bf16;  vt: [bn][D][S] bf16;  cum: [N][S] f32
// mix out: [b][s][n][d] bf16
// 1D grid 1024, block 256 (4 waves). Decode: xcd=L&7 pins 4 heads per XCD
// (KV working set 2 MB < 4 MB XCD-L2); ti descends with L (big blocks first).
// One 64-row Q-tile per block; nj=(ti>>1)+1 KV-tile iters.
// S^T trick: compute S^T = K*Q^T so each lane owns ONE softmax row.
// Ps has its OWN region (no Ks alias) -> only 2 barriers per iter; the
// P write->read is wave-private so in-wave DS ordering suffices.
// LDS map: K [0,16384); V [16384,32768); Ps[64][136] [32768,50176);
// cumbuf[256] [50176,51200). 51200 B -> 3 blocks/CU.
// ---------------------------------------------------------------------------
__global__ __launch_bounds__(256, 3)
void fa_kernel(const bf16* __restrict__ q, const bf16* __restrict__ k,
               const bf16* __restrict__ vt, const float* __restrict__ cum,
               bf16* __restrict__ mix) {
  __shared__ char smem[51200] __attribute__((aligned(16)));
  bf16* Ps = (bf16*)(smem + 32768);             // [64][136]
  float* cumbuf = (float*)(smem + 50176);       // [256]

  const int tid = threadIdx.x, lane = tid & 63, w = tid >> 6;  // w: 0..3
  const int lr = lane & 15, lq = lane >> 4;

  const int L = blockIdx.x;
  const int xcd = L & 7, slot = L >> 3;
  const int bn = xcd + 8 * (slot >> 5);         // 4 heads per XCD
  const int ti = 31 - (slot & 31);              // descending work
  const int n = bn & (NH - 1);
  const int b = bn >> 4;
  const float* cumn = cum + n * S_;

  const int i0 = ti * 64;
  const int nj = (ti >> 1) + 1;                 // KV tiles (128 cols each)

  // Q fragments (B-operand for S^T = K*Q^T): lane n=lr reads Q row lr
  const bf16* qbase = q + ((size_t)bn * S_ + i0 + w * 16) * DH;
  bf16x8 qf[2];
#pragma unroll
  for (int kt = 0; kt < 2; ++kt)
    qf[kt] = *(const bf16x8*)(qbase + lr * DH + kt * 32 + lq * 8);

  f32x4 oacc[4] = {};
  float m_i = -1e30f, l_i = 0.f;                // scalar: this lane's row i=lr
  const int iloc = w * 16 + lr;

  for (int jt = 0; jt < nj; ++jt) {
    const int j0 = jt * 128;
    const bool diag = (jt == nj - 1);
    __syncthreads();   // prior K/V/cum reads done; regions free

    // stage K tile (swizzled: slot (row,c) holds global chunk c^(row&7))
    const char* ksrc = (const char*)(k + ((size_t)bn * S_ + j0) * DH);
#pragma unroll
    for (int t = 0; t < 4; ++t) {
      int cb = t * 4 + w;
      int row = cb * 8 + (lane >> 3);
      int cs = (lane & 7) ^ (row & 7);
      async16(ksrc + row * 128 + cs * 16, smem + cb * 1024 + lane * 16);
    }
    // stage Vt tile (swizzled: slot (row,c) holds global chunk c^(row&15))
    const char* vsrc = (const char*)(vt + (size_t)bn * DH * S_);
#pragma unroll
    for (int t = 0; t < 4; ++t) {
      int cb = t * 4 + w;
      int row = cb * 4 + (lane >> 4);          // d index 0..63
      int cs = (lane & 15) ^ (row & 15);
      async16(vsrc + (size_t)row * (S_ * 2) + j0 * 2 + cs * 16,
              smem + 16384 + cb * 1024 + lane * 16);
    }
    // stage cum window: cumbuf[t] = cumn[clamp(i0-j0-127+t)]
    {
      int src = i0 - j0 - 127 + tid;
      src = src < 0 ? 0 : (src > S_ - 1 ? S_ - 1 : src);
      cumbuf[tid] = cumn[src];
    }
    __syncthreads();   // staging complete

    // S^T = K * Q^T: sa[nt][r] = S[i=i0+iloc][j = j0 + nt*16 + lq*4 + r]
    f32x4 sa[8] = {};
#pragma unroll
    for (int kt = 0; kt < 2; ++kt)
#pragma unroll
      for (int nt = 0; nt < 8; ++nt) {
        int krow = nt * 16 + lr;
        bf16x8 kf = *(const bf16x8*)(smem + krow * 128 +
                        (((kt * 4 + lq) ^ (krow & 7)) << 4));
        sa[nt] = MFMA16(kf, qf[kt], sa[nt]);
      }

    // scale + bias (+ causal mask on diagonal tile); single row per lane
    const int doff = i0 - j0;     // 0 or 64 on diagonal tile
    float rmax = -1e30f;
    if (!diag) {
#pragma unroll
      for (int nt = 0; nt < 8; ++nt)
#pragma unroll
        for (int r = 0; r < 4; ++r) {
          int rel = iloc - nt * 16 - lq * 4 - r;
          float val = sa[nt][r] * SCALE + cumbuf[127 + rel];
          sa[nt][r] = val;
          rmax = fmaxf(rmax, val);
        }
    } else {
#pragma unroll
      for (int nt = 0; nt < 8; ++nt)
#pragma unroll
        for (int r = 0; r < 4; ++r) {
          int rel = iloc - nt * 16 - lq * 4 - r;
          float val = (doff + rel >= 0) ? sa[nt][r] * SCALE + cumbuf[127 + rel]
                                        : -1e30f;
          sa[nt][r] = val;
          rmax = fmaxf(rmax, val);
        }
    }
    // online softmax: combine quads (lanes lr, lr+16, lr+32, lr+48 share row)
    float mx = fmaxf(rmax, __shfl_xor(rmax, 16));
    mx = fmaxf(mx, __shfl_xor(mx, 32));
    float newm = fmaxf(m_i, mx);
    float al = __expf(m_i - newm);
    m_i = newm;
    float rs = 0.f;
#pragma unroll
    for (int nt = 0; nt < 8; ++nt)
#pragma unroll
      for (int r = 0; r < 4; ++r) {
        float p = __expf(sa[nt][r] - newm);
        sa[nt][r] = p;
        rs += p;
      }
    rs += __shfl_xor(rs, 16);
    rs += __shfl_xor(rs, 32);
    l_i = l_i * al + rs;
    // rescale O (O rows indexed by lq*4+r; alpha lives at lane lq*4+r)
    float alr[4];
#pragma unroll
    for (int r = 0; r < 4; ++r) alr[r] = __shfl(al, lq * 4 + r);
#pragma unroll
    for (int dt = 0; dt < 4; ++dt)
#pragma unroll
      for (int r = 0; r < 4; ++r) oacc[dt][r] *= alr[r];

    // write P row iloc: 4 consecutive j per reg quad -> b64 stores
#pragma unroll
    for (int nt = 0; nt < 8; ++nt) {
      bf16 pk[4];
#pragma unroll
      for (int r = 0; r < 4; ++r) pk[r] = __float2bfloat16(sa[nt][r]);
      *(uint64_t*)(Ps + iloc * 136 + nt * 16 + lq * 4) = *(const uint64_t*)pk;
    }

    // O += P V (wave-private P rows; in-wave DS ordering suffices)
#pragma unroll
    for (int kt2 = 0; kt2 < 4; ++kt2) {
      bf16x8 pf = *(const bf16x8*)(Ps + (w * 16 + lr) * 136 + kt2 * 32 + lq * 8);
#pragma unroll
      for (int dt = 0; dt < 4; ++dt) {
        int vrow = dt * 16 + lr;
        bf16x8 vf = *(const bf16x8*)(smem + 16384 + vrow * 256 +
                        (((kt2 * 4 + lq) ^ (vrow & 15)) << 4));
        oacc[dt] = MFMA16(pf, vf, oacc[dt]);
      }
    }
  }

  // epilogue: mix[b][s][n][d];  l for O-row lq*4+r lives at lane lq*4+r
  float lr4[4];
#pragma unroll
  for (int r = 0; r < 4; ++r) lr4[r] = __shfl(l_i, lq * 4 + r);
#pragma unroll
  for (int dt = 0; dt < 4; ++dt)
#pragma unroll
    for (int r = 0; r < 4; ++r) {
      int i = i0 + w * 16 + lq * 4 + r;
      int d = dt * 16 + lr;
      mix[((size_t)(b * S_ + i) * NH + n) * DH + d] =
          __float2bfloat16(oacc[dt][r] / lr4[r]);
    }
}

// ---------------------------------------------------------------------------
extern "C" void kernel_launch(void* const* d_in, const int* in_sizes, int n_in,
                              void* d_out, int out_size, void* d_ws, size_t ws_size,
                              hipStream_t stream) {
  const float* x     = (const float*)d_in[0];   // [B,S,H] f32
  const float* qkv   = (const float*)d_in[1];   // [H,3,N,D] f32 == [1024][3072]
  const float* out_w = (const float*)d_in[2];   // [N,D,H] f32   == [1024][1024]
  const float* rpe   = (const float*)d_in[3];   // [N,S] f32
  float* out = (float*)d_out;                   // [B,S,H] f32

  char* ws = (char*)d_ws;
  bf16* qkvT  = (bf16*)(ws + 0);          // [3072][1024] bf16   6291456 B
  bf16* outwT = (bf16*)(ws + 6291456);    // [1024][1024] bf16   2097152 B
  bf16* xb    = (bf16*)(ws + 8388608);    // [4096][1024] bf16   8388608 B
  bf16* qb    = (bf16*)(ws + 16777216);   // [bn][S][D]          8388608 B
  bf16* kb    = (bf16*)(ws + 25165824);   // [bn][S][D]          8388608 B
  bf16* vtb   = (bf16*)(ws + 33554432);   // [bn][D][S]          8388608 B
  bf16* mixb  = (bf16*)(ws + 41943040);   // [b][s][n][d]        8388608 B
  float* cum  = (float*)(ws + 50331648);  // [N][S] f32           131072 B

  // 1. convert x; pre-transpose+convert weights
  convert_f32_bf16<<<4096, 256, 0, stream>>>(x, xb, 4096 * 1024);
  transpose_f32_bf16<<<dim3(3072 / 32, 1024 / 32), 256, 0, stream>>>(qkv, qkvT, 1024, 3072);
  transpose_f32_bf16<<<dim3(1024 / 32, 1024 / 32), 256, 0, stream>>>(out_w, outwT, 1024, 1024);
  // 2. rpe cumsum
  rpe_scan<<<NH, 256, 0, stream>>>(rpe, cum);
  // 3. QKV projection (V written pre-transposed)
  gemm_bt<0><<<dim3(3072 / 128, 4096 / 128), 256, 0, stream>>>(xb, qkvT, qb, kb, vtb, nullptr);
  // 4. attention
  fa_kernel<<<1024, 256, 0, stream>>>(qb, kb, vtb, cum, mixb);
  // 5. output projection (f32 out)
  gemm_bt<1><<<dim3(1024 / 128, 4096 / 128), 256, 0, stream>>>(mixb, outwT, nullptr, nullptr, nullptr, out);
}